// Round 5
// baseline (934.952 us; speedup 1.0000x reference)
//
#include <hip/hip_runtime.h>

constexpr int B_ = 32, C_ = 256, H_ = 32, W_ = 32, M_ = 1024;
constexpr int NH = 4, DK = 16, DV = 64;
constexpr float EPS = 1e-5f;

// ---------------- Kernel 1: qkv = W(144x256) @ x(256xM) per batch, + BN ----
__global__ __launch_bounds__(256) void k_qkv(
    const float* __restrict__ x, const float* __restrict__ w,
    const float* __restrict__ qg, const float* __restrict__ qb,
    const float* __restrict__ qm, const float* __restrict__ qv,
    const float* __restrict__ vg, const float* __restrict__ vb,
    const float* __restrict__ vm, const float* __restrict__ vv,
    float* __restrict__ q_out, float* __restrict__ k_out,
    float* __restrict__ v_out)
{
    __shared__ float xs[64][64];    // 16 KB
    __shared__ float wsh[144][64];  // 36.9 KB
    const int b   = blockIdx.x >> 4;
    const int m0  = (blockIdx.x & 15) * 64;
    const int tid = threadIdx.x;
    const int ml  = tid & 15;
    const int og  = tid >> 4;

    float acc[4][9];
#pragma unroll
    for (int i = 0; i < 4; i++)
#pragma unroll
        for (int j = 0; j < 9; j++) acc[i][j] = 0.f;

    for (int c0 = 0; c0 < C_; c0 += 64) {
        __syncthreads();
#pragma unroll
        for (int i = 0; i < 4; i++) {            // 4096 x = 1024 float4
            int f4 = tid + 256 * i;
            int ci = f4 >> 4, mf = (f4 & 15) * 4;
            *reinterpret_cast<float4*>(&xs[ci][mf]) =
                *reinterpret_cast<const float4*>(&x[(b * C_ + c0 + ci) * M_ + m0 + mf]);
        }
#pragma unroll
        for (int i = 0; i < 9; i++) {            // 9216 w = 2304 float4
            int f4 = tid + 256 * i;
            int o = f4 >> 4, cf = (f4 & 15) * 4;
            *reinterpret_cast<float4*>(&wsh[o][cf]) =
                *reinterpret_cast<const float4*>(&w[o * C_ + c0 + cf]);
        }
        __syncthreads();
#pragma unroll 2
        for (int ci = 0; ci < 64; ci++) {
            float4 xv = *reinterpret_cast<const float4*>(&xs[ci][ml * 4]);
#pragma unroll
            for (int j = 0; j < 9; j++) {
                float wv = wsh[og + 16 * j][ci];
                acc[0][j] = fmaf(wv, xv.x, acc[0][j]);
                acc[1][j] = fmaf(wv, xv.y, acc[1][j]);
                acc[2][j] = fmaf(wv, xv.z, acc[2][j]);
                acc[3][j] = fmaf(wv, xv.w, acc[3][j]);
            }
        }
    }

    const int mbase = m0 + ml * 4;
#pragma unroll
    for (int j = 0; j < 9; j++) {
        const int o = og + 16 * j;
        if (o < 64) {                         // q channel: BN then [b][m][n][k]
            float inv = qg[o] * rsqrtf(qv[o] + EPS);
            float add = qb[o] - qm[o] * inv;
            int n = o >> 4, k = o & 15;
#pragma unroll
            for (int i = 0; i < 4; i++)
                q_out[((b * M_ + mbase + i) * NH + n) * DK + k] =
                    acc[i][j] * inv + add;
        } else if (o < 80) {                  // k logits: [b][k][m]
            int kk = o - 64;
#pragma unroll
            for (int i = 0; i < 4; i++)
                k_out[(b * DK + kk) * M_ + mbase + i] = acc[i][j];
        } else {                              // v channel: BN then [b][m][vd]
            int vd = o - 80;
            float inv = vg[vd] * rsqrtf(vv[vd] + EPS);
            float add = vb[vd] - vm[vd] * inv;
#pragma unroll
            for (int i = 0; i < 4; i++)
                v_out[(b * M_ + mbase + i) * DV + vd] = acc[i][j] * inv + add;
        }
    }
}

// ---------------- Kernel 2: softmax over M per (b,k) row, in place ---------
__global__ __launch_bounds__(256) void k_softmax(float* __restrict__ kl)
{
    float* p = kl + (size_t)blockIdx.x * M_;
    const int tid = threadIdx.x;
    float v[4];
    float mx = -1e30f;
#pragma unroll
    for (int i = 0; i < 4; i++) { v[i] = p[tid + 256 * i]; mx = fmaxf(mx, v[i]); }
#pragma unroll
    for (int off = 32; off >= 1; off >>= 1) mx = fmaxf(mx, __shfl_xor(mx, off));
    __shared__ float red[8];
    if ((tid & 63) == 0) red[tid >> 6] = mx;
    __syncthreads();
    mx = fmaxf(fmaxf(red[0], red[1]), fmaxf(red[2], red[3]));
    float s = 0.f;
#pragma unroll
    for (int i = 0; i < 4; i++) { v[i] = __expf(v[i] - mx); s += v[i]; }
#pragma unroll
    for (int off = 32; off >= 1; off >>= 1) s += __shfl_xor(s, off);
    if ((tid & 63) == 0) red[4 + (tid >> 6)] = s;
    __syncthreads();
    s = red[4] + red[5] + red[6] + red[7];
    float inv = 1.f / s;
#pragma unroll
    for (int i = 0; i < 4; i++) p[tid + 256 * i] = v[i] * inv;
}

// ---------------- Kernel 3: content_lam[b,k,vd] = sum_m ksm * v ------------
__global__ __launch_bounds__(256) void k_clam(
    const float* __restrict__ ksm, const float* __restrict__ vbn,
    float* __restrict__ clam)
{
    const int b   = blockIdx.x >> 3;
    const int m0  = (blockIdx.x & 7) * 128;
    const int tid = threadIdx.x;
    const int vd  = tid & 63;
    const int kq  = tid >> 6;
    float acc[4] = {0.f, 0.f, 0.f, 0.f};
    for (int mi = 0; mi < 128; mi++) {
        const int m = m0 + mi;
        const float vvv = vbn[(b * M_ + m) * DV + vd];
#pragma unroll
        for (int j = 0; j < 4; j++)
            acc[j] = fmaf(ksm[(b * DK + kq + 4 * j) * M_ + m], vvv, acc[j]);
    }
#pragma unroll
    for (int j = 0; j < 4; j++)
        atomicAdd(&clam[(b * DK + kq + 4 * j) * DV + vd], acc[j]);
}

// ---------------- Kernel 4: fused 7x7 conv (pos_lam) + final matmul --------
// grid 32 b * 16 row-pairs (2 rows).  512 thr: vd=tid&63, pg=tid>>6 (4 px).
// v read DIRECT from global (L2-resident, 256B coalesced) into vr[10] regs.
// LDS only: ostage[64][132] (33.8 KB, per-row flush), lw_s, cl_s -> ~41 KB
// => 2-3 blocks/CU.  Stores via proven LDS transpose -> coalesced float4.
__global__ __launch_bounds__(512, 4) void k_fuse(
    const float* __restrict__ vbn, const float* __restrict__ qbn,
    const float* __restrict__ clam,
    const float* __restrict__ lw, const float* __restrict__ lb,
    float* __restrict__ out)
{
    __shared__ float ostage[64][132];      // 33.8 KB; stride%4==0 -> b128 ok
    __shared__ float lw_s[16 * 49];
    __shared__ float cl_s[16 * 64];
    __shared__ float lb_s[16];

    const int b   = blockIdx.x >> 4;
    const int rt  = blockIdx.x & 15;
    const int h0  = rt * 2;
    const int tid = threadIdx.x;

    for (int i = tid; i < 784; i += 512) lw_s[i] = lw[i];
    if (tid < 256)
        *reinterpret_cast<float4*>(&cl_s[tid * 4]) =
            *reinterpret_cast<const float4*>(&clam[b * DK * DV + tid * 4]);
    if (tid < 16) lb_s[tid] = lb[tid];
    __syncthreads();

    const int vd  = tid & 63;
    const int pg  = tid >> 6;       // 0..7: pixel column group
    const int px0 = pg * 4;
    const float* vb_b = vbn + (size_t)b * M_ * DV + vd;

    for (int grp = 0; grp < 2; grp++) {     // output row h0+grp
        float plam[4][16];
#pragma unroll
        for (int ip = 0; ip < 4; ip++)
#pragma unroll
            for (int k = 0; k < 16; k++) plam[ip][k] = 0.f;

#pragma unroll
        for (int dy = 0; dy < 7; dy++) {
            const int gr = h0 + grp - 3 + dy;      // global row (block-uniform)
            float vr[10];                          // cols px0-3 .. px0+6
            if (gr >= 0 && gr < H_) {
#pragma unroll
                for (int j = 0; j < 10; j++) {
                    const int col = px0 - 3 + j;   // wave-uniform validity
                    vr[j] = (col >= 0 && col < W_)
                          ? vb_b[(gr * W_ + col) * DV] : 0.f;
                }
            } else {
#pragma unroll
                for (int j = 0; j < 10; j++) vr[j] = 0.f;
            }
#pragma unroll
            for (int dx = 0; dx < 7; dx++) {
                float lwv[16];
#pragma unroll
                for (int k = 0; k < 16; k++) lwv[k] = lw_s[k * 49 + dy * 7 + dx];
#pragma unroll
                for (int ip = 0; ip < 4; ip++) {
                    const float vv = vr[ip + dx];
#pragma unroll
                    for (int k = 0; k < 16; k++)
                        plam[ip][k] = fmaf(vv, lwv[k], plam[ip][k]);
                }
            }
        }
        // epilogue: 4 pixels -> ostage[vd][p*4..p*4+3]
        const int mrow = (h0 + grp) * W_;
#pragma unroll
        for (int ip = 0; ip < 4; ip++) {
            const int p = px0 + ip;                // 0..31 within row
            const int m = mrow + p;
            float lamv[16];
#pragma unroll
            for (int k = 0; k < 16; k++)
                lamv[k] = plam[ip][k] + cl_s[k * DV + vd] + lb_s[k];
            const float* qp = qbn + (size_t)(b * M_ + m) * NH * DK;
            float4 ov;
            float* ovp = reinterpret_cast<float*>(&ov);
#pragma unroll
            for (int n = 0; n < 4; n++) {
                const float4* q4 = reinterpret_cast<const float4*>(qp + n * DK);
                float4 qa = q4[0], qb4 = q4[1], qc = q4[2], qd = q4[3];
                ovp[n] = qa.x * lamv[0] + qa.y * lamv[1] + qa.z * lamv[2] + qa.w * lamv[3]
                       + qb4.x * lamv[4] + qb4.y * lamv[5] + qb4.z * lamv[6] + qb4.w * lamv[7]
                       + qc.x * lamv[8] + qc.y * lamv[9] + qc.z * lamv[10] + qc.w * lamv[11]
                       + qd.x * lamv[12] + qd.y * lamv[13] + qd.z * lamv[14] + qd.w * lamv[15];
            }
            *reinterpret_cast<float4*>(&ostage[vd][p * 4]) = ov;
        }
        __syncthreads();
        // flush this row: 2048 float4, lanes consecutive -> coalesced
        {
            const int mrow4 = mrow * 4;
            for (int i4 = tid; i4 < 2048; i4 += 512) {
                const int vdw  = i4 >> 5;          // 32 float4 per vd
                const int off4 = (i4 & 31) * 4;
                float4 val = *reinterpret_cast<const float4*>(&ostage[vdw][off4]);
                *reinterpret_cast<float4*>(
                    out + (size_t)b * (C_ * M_) + (size_t)vdw * 4096 + mrow4 + off4) = val;
            }
        }
        __syncthreads();
    }
}

extern "C" void kernel_launch(void* const* d_in, const int* in_sizes, int n_in,
                              void* d_out, int out_size, void* d_ws, size_t ws_size,
                              hipStream_t stream)
{
    (void)in_sizes; (void)n_in; (void)out_size; (void)ws_size;
    const float* x   = (const float*)d_in[0];
    const float* w   = (const float*)d_in[1];
    const float* qg  = (const float*)d_in[2];
    const float* qb  = (const float*)d_in[3];
    const float* qm  = (const float*)d_in[4];
    const float* qvr = (const float*)d_in[5];
    const float* vg  = (const float*)d_in[6];
    const float* vb  = (const float*)d_in[7];
    const float* vm  = (const float*)d_in[8];
    const float* vvr = (const float*)d_in[9];
    const float* lw  = (const float*)d_in[10];
    const float* lb  = (const float*)d_in[11];
    float* out = (float*)d_out;

    float* ws   = (float*)d_ws;
    float* q_bn = ws;                  // [b][m][n][k]  2,097,152 f
    float* v_bn = ws + 2097152;        // [b][m][vd]    2,097,152 f
    float* k_bf = ws + 4194304;        // [b][k][m]       524,288 f (in-place sm)
    float* clam = ws + 4718592;        // [b][k][vd]       32,768 f

    hipMemsetAsync(clam, 0, 32768 * sizeof(float), stream);
    hipLaunchKernelGGL(k_qkv, dim3(512), dim3(256), 0, stream,
                       x, w, qg, qb, qm, qvr, vg, vb, vm, vvr, q_bn, k_bf, v_bn);
    hipLaunchKernelGGL(k_softmax, dim3(512), dim3(256), 0, stream, k_bf);
    hipLaunchKernelGGL(k_clam, dim3(256), dim3(256), 0, stream, k_bf, v_bn, clam);
    hipLaunchKernelGGL(k_fuse, dim3(512), dim3(512), 0, stream,
                       v_bn, q_bn, clam, lw, lb, out);
}

// Round 7
// 830.716 us; speedup vs baseline: 1.1255x; 1.1255x over previous
//
#include <hip/hip_runtime.h>

constexpr int B_ = 32, C_ = 256, H_ = 32, W_ = 32, M_ = 1024;
constexpr int NH = 4, DK = 16, DV = 64;
constexpr float EPS = 1e-5f;

// ---------------- Kernel 1: qkv = W(144x256) @ x(256xM) per batch, + BN ----
__global__ __launch_bounds__(256) void k_qkv(
    const float* __restrict__ x, const float* __restrict__ w,
    const float* __restrict__ qg, const float* __restrict__ qb,
    const float* __restrict__ qm, const float* __restrict__ qv,
    const float* __restrict__ vg, const float* __restrict__ vb,
    const float* __restrict__ vm, const float* __restrict__ vv,
    float* __restrict__ q_out, float* __restrict__ k_out,
    float* __restrict__ v_out)
{
    __shared__ float xs[64][64];    // 16 KB
    __shared__ float wsh[144][64];  // 36.9 KB
    const int b   = blockIdx.x >> 4;
    const int m0  = (blockIdx.x & 15) * 64;
    const int tid = threadIdx.x;
    const int ml  = tid & 15;
    const int og  = tid >> 4;

    float acc[4][9];
#pragma unroll
    for (int i = 0; i < 4; i++)
#pragma unroll
        for (int j = 0; j < 9; j++) acc[i][j] = 0.f;

    for (int c0 = 0; c0 < C_; c0 += 64) {
        __syncthreads();
#pragma unroll
        for (int i = 0; i < 4; i++) {            // 4096 x = 1024 float4
            int f4 = tid + 256 * i;
            int ci = f4 >> 4, mf = (f4 & 15) * 4;
            *reinterpret_cast<float4*>(&xs[ci][mf]) =
                *reinterpret_cast<const float4*>(&x[(b * C_ + c0 + ci) * M_ + m0 + mf]);
        }
#pragma unroll
        for (int i = 0; i < 9; i++) {            // 9216 w = 2304 float4
            int f4 = tid + 256 * i;
            int o = f4 >> 4, cf = (f4 & 15) * 4;
            *reinterpret_cast<float4*>(&wsh[o][cf]) =
                *reinterpret_cast<const float4*>(&w[o * C_ + c0 + cf]);
        }
        __syncthreads();
#pragma unroll 2
        for (int ci = 0; ci < 64; ci++) {
            float4 xv = *reinterpret_cast<const float4*>(&xs[ci][ml * 4]);
#pragma unroll
            for (int j = 0; j < 9; j++) {
                float wv = wsh[og + 16 * j][ci];
                acc[0][j] = fmaf(wv, xv.x, acc[0][j]);
                acc[1][j] = fmaf(wv, xv.y, acc[1][j]);
                acc[2][j] = fmaf(wv, xv.z, acc[2][j]);
                acc[3][j] = fmaf(wv, xv.w, acc[3][j]);
            }
        }
    }

    const int mbase = m0 + ml * 4;
#pragma unroll
    for (int j = 0; j < 9; j++) {
        const int o = og + 16 * j;
        if (o < 64) {                         // q channel: BN then [b][m][n][k]
            float inv = qg[o] * rsqrtf(qv[o] + EPS);
            float add = qb[o] - qm[o] * inv;
            int n = o >> 4, k = o & 15;
#pragma unroll
            for (int i = 0; i < 4; i++)
                q_out[((b * M_ + mbase + i) * NH + n) * DK + k] =
                    acc[i][j] * inv + add;
        } else if (o < 80) {                  // k logits: [b][k][m]
            int kk = o - 64;
#pragma unroll
            for (int i = 0; i < 4; i++)
                k_out[(b * DK + kk) * M_ + mbase + i] = acc[i][j];
        } else {                              // v channel: BN then [b][m][vd]
            int vd = o - 80;
            float inv = vg[vd] * rsqrtf(vv[vd] + EPS);
            float add = vb[vd] - vm[vd] * inv;
#pragma unroll
            for (int i = 0; i < 4; i++)
                v_out[(b * M_ + mbase + i) * DV + vd] = acc[i][j] * inv + add;
        }
    }
}

// ---------------- Kernel 2: softmax over M per (b,k) row, in place ---------
__global__ __launch_bounds__(256) void k_softmax(float* __restrict__ kl)
{
    float* p = kl + (size_t)blockIdx.x * M_;
    const int tid = threadIdx.x;
    float v[4];
    float mx = -1e30f;
#pragma unroll
    for (int i = 0; i < 4; i++) { v[i] = p[tid + 256 * i]; mx = fmaxf(mx, v[i]); }
#pragma unroll
    for (int off = 32; off >= 1; off >>= 1) mx = fmaxf(mx, __shfl_xor(mx, off));
    __shared__ float red[8];
    if ((tid & 63) == 0) red[tid >> 6] = mx;
    __syncthreads();
    mx = fmaxf(fmaxf(red[0], red[1]), fmaxf(red[2], red[3]));
    float s = 0.f;
#pragma unroll
    for (int i = 0; i < 4; i++) { v[i] = __expf(v[i] - mx); s += v[i]; }
#pragma unroll
    for (int off = 32; off >= 1; off >>= 1) s += __shfl_xor(s, off);
    if ((tid & 63) == 0) red[4 + (tid >> 6)] = s;
    __syncthreads();
    s = red[4] + red[5] + red[6] + red[7];
    float inv = 1.f / s;
#pragma unroll
    for (int i = 0; i < 4; i++) p[tid + 256 * i] = v[i] * inv;
}

// ---------------- Kernel 3: content_lam[b,k,vd] = sum_m ksm * v ------------
__global__ __launch_bounds__(256) void k_clam(
    const float* __restrict__ ksm, const float* __restrict__ vbn,
    float* __restrict__ clam)
{
    const int b   = blockIdx.x >> 3;
    const int m0  = (blockIdx.x & 7) * 128;
    const int tid = threadIdx.x;
    const int vd  = tid & 63;
    const int kq  = tid >> 6;
    float acc[4] = {0.f, 0.f, 0.f, 0.f};
    for (int mi = 0; mi < 128; mi++) {
        const int m = m0 + mi;
        const float vvv = vbn[(b * M_ + m) * DV + vd];
#pragma unroll
        for (int j = 0; j < 4; j++)
            acc[j] = fmaf(ksm[(b * DK + kq + 4 * j) * M_ + m], vvv, acc[j]);
    }
#pragma unroll
    for (int j = 0; j < 4; j++)
        atomicAdd(&clam[(b * DK + kq + 4 * j) * DV + vd], acc[j]);
}

// ---------------- Kernel 4: fused 7x7 conv (pos_lam) + final matmul --------
// Round-3 structure (v_s halo + ostage flush: FETCH 16MB/WRITE 36MB proven),
// upgraded to 1024 threads = 16 waves = 4 waves/SIMD (was 2).
// grid 32 b * 8 tiles of 4 rows.  wave w: rhalf=w>>3 (row in pair), pg=w&7
// (4-px column group), vd=lane.  Two iterations: rows {0,1} then {2,3}.
// NO min-waves launch_bounds clause (round-4/5 spill disaster, VGPR 64).
__global__ __launch_bounds__(1024) void k_fuse(
    const float* __restrict__ vbn, const float* __restrict__ qbn,
    const float* __restrict__ clam,
    const float* __restrict__ lw, const float* __restrict__ lb,
    float* __restrict__ out)
{
    __shared__ float v_s[10 * 32 * 64];    // 80 KB: global rows h0-3 .. h0+6
    __shared__ float ostage[64][260];      // 66.6 KB; 260%4==0 -> 16B aligned
    __shared__ float lw_s[16 * 49];
    __shared__ float cl_s[16 * 64];
    __shared__ float lb_s[16];

    const int b   = blockIdx.x >> 3;
    const int rt  = blockIdx.x & 7;
    const int h0  = rt * 4;
    const int tid = threadIdx.x;

    for (int i4 = tid; i4 < 5120; i4 += 1024) {   // 20480 floats as float4
        int r   = i4 >> 9;                 // staged row 0..9 = global h0-3+r
        int rem = (i4 & 511) * 4;
        int gr  = h0 - 3 + r;
        float4 val = make_float4(0.f, 0.f, 0.f, 0.f);
        if (gr >= 0 && gr < H_)
            val = *reinterpret_cast<const float4*>(&vbn[(b * M_ + gr * W_) * DV + rem]);
        *reinterpret_cast<float4*>(&v_s[r * 2048 + rem]) = val;
    }
    if (tid < 784) lw_s[tid] = lw[tid];
    if (tid < 256)                              // 256 threads x float4 = 1024 f
        *reinterpret_cast<float4*>(&cl_s[tid * 4]) =
            *reinterpret_cast<const float4*>(&clam[b * DK * DV + tid * 4]);
    if (tid < 16) lb_s[tid] = lb[tid];
    __syncthreads();

    const int vd    = tid & 63;
    const int wv    = tid >> 6;       // wave 0..15
    const int rhalf = wv >> 3;        // row within pair
    const int pg    = wv & 7;         // column group
    const int px0   = pg * 4;

    for (int it = 0; it < 2; it++) {        // row pair {2it, 2it+1}
        const int grp = it * 2 + rhalf;     // row within tile 0..3
        float plam[4][16];
#pragma unroll
        for (int ip = 0; ip < 4; ip++)
#pragma unroll
            for (int k = 0; k < 16; k++) plam[ip][k] = 0.f;

#pragma unroll
        for (int dy = 0; dy < 7; dy++) {
            const int rbase = (grp + dy) * W_;   // staged row index * 32
            float vr[10];                        // cols px0-3 .. px0+6
#pragma unroll
            for (int j = 0; j < 10; j++) {
                const int col = px0 - 3 + j;     // wave-uniform validity
                vr[j] = (col >= 0 && col < W_) ? v_s[(rbase + col) * DV + vd] : 0.f;
            }
#pragma unroll
            for (int dx = 0; dx < 7; dx++) {
                float lwv[16];
#pragma unroll
                for (int k = 0; k < 16; k++) lwv[k] = lw_s[k * 49 + dy * 7 + dx];
#pragma unroll
                for (int ip = 0; ip < 4; ip++) {
                    const float vvv = vr[ip + dx];
#pragma unroll
                    for (int k = 0; k < 16; k++)
                        plam[ip][k] = fmaf(vvv, lwv[k], plam[ip][k]);
                }
            }
        }
        // epilogue: 4 pixels of row grp -> ostage
#pragma unroll
        for (int ip = 0; ip < 4; ip++) {
            const int p = grp * 32 + px0 + ip;   // 0..127 within tile
            const int m = h0 * W_ + p;
            float lamv[16];
#pragma unroll
            for (int k = 0; k < 16; k++)
                lamv[k] = plam[ip][k] + cl_s[k * DV + vd] + lb_s[k];
            const float* qp = qbn + (size_t)(b * M_ + m) * NH * DK;
            float4 ov;
            float* ovp = reinterpret_cast<float*>(&ov);
#pragma unroll
            for (int n = 0; n < 4; n++) {
                const float4* q4 = reinterpret_cast<const float4*>(qp + n * DK);
                float4 qa = q4[0], qb4 = q4[1], qc = q4[2], qd = q4[3];
                ovp[n] = qa.x * lamv[0] + qa.y * lamv[1] + qa.z * lamv[2] + qa.w * lamv[3]
                       + qb4.x * lamv[4] + qb4.y * lamv[5] + qb4.z * lamv[6] + qb4.w * lamv[7]
                       + qc.x * lamv[8] + qc.y * lamv[9] + qc.z * lamv[10] + qc.w * lamv[11]
                       + qd.x * lamv[12] + qd.y * lamv[13] + qd.z * lamv[14] + qd.w * lamv[15];
            }
            *reinterpret_cast<float4*>(&ostage[vd][(p & 63) * 4]) = ov;
        }
        __syncthreads();
        // flush 2 rows = 64 px: 4096 float4, coalesced (1KB per vd row)
        {
            const int mb4 = (h0 + it * 2) * W_ * 4;
            for (int i4 = tid; i4 < 4096; i4 += 1024) {
                const int vdw  = i4 >> 6;
                const int off4 = (i4 & 63) * 4;
                float4 val = *reinterpret_cast<const float4*>(&ostage[vdw][off4]);
                *reinterpret_cast<float4*>(
                    out + (size_t)b * (C_ * M_) + (size_t)vdw * 4096 + mb4 + off4) = val;
            }
        }
        __syncthreads();
    }
}

extern "C" void kernel_launch(void* const* d_in, const int* in_sizes, int n_in,
                              void* d_out, int out_size, void* d_ws, size_t ws_size,
                              hipStream_t stream)
{
    (void)in_sizes; (void)n_in; (void)out_size; (void)ws_size;
    const float* x   = (const float*)d_in[0];
    const float* w   = (const float*)d_in[1];
    const float* qg  = (const float*)d_in[2];
    const float* qb  = (const float*)d_in[3];
    const float* qm  = (const float*)d_in[4];
    const float* qvr = (const float*)d_in[5];
    const float* vg  = (const float*)d_in[6];
    const float* vb  = (const float*)d_in[7];
    const float* vm  = (const float*)d_in[8];
    const float* vvr = (const float*)d_in[9];
    const float* lw  = (const float*)d_in[10];
    const float* lb  = (const float*)d_in[11];
    float* out = (float*)d_out;

    float* ws   = (float*)d_ws;
    float* q_bn = ws;                  // [b][m][n][k]  2,097,152 f
    float* v_bn = ws + 2097152;        // [b][m][vd]    2,097,152 f
    float* k_bf = ws + 4194304;        // [b][k][m]       524,288 f (in-place sm)
    float* clam = ws + 4718592;        // [b][k][vd]       32,768 f

    hipMemsetAsync(clam, 0, 32768 * sizeof(float), stream);
    hipLaunchKernelGGL(k_qkv, dim3(512), dim3(256), 0, stream,
                       x, w, qg, qb, qm, qvr, vg, vb, vm, vvr, q_bn, k_bf, v_bn);
    hipLaunchKernelGGL(k_softmax, dim3(512), dim3(256), 0, stream, k_bf);
    hipLaunchKernelGGL(k_clam, dim3(256), dim3(256), 0, stream, k_bf, v_bn, clam);
    hipLaunchKernelGGL(k_fuse, dim3(256), dim3(1024), 0, stream,
                       v_bn, q_bn, clam, lw, lb, out);
}

// Round 8
// 689.317 us; speedup vs baseline: 1.3563x; 1.2051x over previous
//
#include <hip/hip_runtime.h>

constexpr int B_ = 32, C_ = 256, H_ = 32, W_ = 32, M_ = 1024;
constexpr int NH = 4, DK = 16, DV = 64;
constexpr float EPS = 1e-5f;

// ---------------- Kernel 1: qkv = W(144x256) @ x(256xM) per batch, + BN ----
__global__ __launch_bounds__(256) void k_qkv(
    const float* __restrict__ x, const float* __restrict__ w,
    const float* __restrict__ qg, const float* __restrict__ qb,
    const float* __restrict__ qm, const float* __restrict__ qv,
    const float* __restrict__ vg, const float* __restrict__ vb,
    const float* __restrict__ vm, const float* __restrict__ vv,
    float* __restrict__ q_out, float* __restrict__ k_out,
    float* __restrict__ v_out)
{
    __shared__ float xs[64][64];    // 16 KB
    __shared__ float wsh[144][64];  // 36.9 KB
    const int b   = blockIdx.x >> 4;
    const int m0  = (blockIdx.x & 15) * 64;
    const int tid = threadIdx.x;
    const int ml  = tid & 15;
    const int og  = tid >> 4;

    float acc[4][9];
#pragma unroll
    for (int i = 0; i < 4; i++)
#pragma unroll
        for (int j = 0; j < 9; j++) acc[i][j] = 0.f;

    for (int c0 = 0; c0 < C_; c0 += 64) {
        __syncthreads();
#pragma unroll
        for (int i = 0; i < 4; i++) {            // 4096 x = 1024 float4
            int f4 = tid + 256 * i;
            int ci = f4 >> 4, mf = (f4 & 15) * 4;
            *reinterpret_cast<float4*>(&xs[ci][mf]) =
                *reinterpret_cast<const float4*>(&x[(b * C_ + c0 + ci) * M_ + m0 + mf]);
        }
#pragma unroll
        for (int i = 0; i < 9; i++) {            // 9216 w = 2304 float4
            int f4 = tid + 256 * i;
            int o = f4 >> 4, cf = (f4 & 15) * 4;
            *reinterpret_cast<float4*>(&wsh[o][cf]) =
                *reinterpret_cast<const float4*>(&w[o * C_ + c0 + cf]);
        }
        __syncthreads();
#pragma unroll 2
        for (int ci = 0; ci < 64; ci++) {
            float4 xv = *reinterpret_cast<const float4*>(&xs[ci][ml * 4]);
#pragma unroll
            for (int j = 0; j < 9; j++) {
                float wv = wsh[og + 16 * j][ci];
                acc[0][j] = fmaf(wv, xv.x, acc[0][j]);
                acc[1][j] = fmaf(wv, xv.y, acc[1][j]);
                acc[2][j] = fmaf(wv, xv.z, acc[2][j]);
                acc[3][j] = fmaf(wv, xv.w, acc[3][j]);
            }
        }
    }

    const int mbase = m0 + ml * 4;
#pragma unroll
    for (int j = 0; j < 9; j++) {
        const int o = og + 16 * j;
        if (o < 64) {                         // q channel: BN then [b][m][n][k]
            float inv = qg[o] * rsqrtf(qv[o] + EPS);
            float add = qb[o] - qm[o] * inv;
            int n = o >> 4, k = o & 15;
#pragma unroll
            for (int i = 0; i < 4; i++)
                q_out[((b * M_ + mbase + i) * NH + n) * DK + k] =
                    acc[i][j] * inv + add;
        } else if (o < 80) {                  // k logits: [b][k][m]
            int kk = o - 64;
#pragma unroll
            for (int i = 0; i < 4; i++)
                k_out[(b * DK + kk) * M_ + mbase + i] = acc[i][j];
        } else {                              // v channel: BN then [b][m][vd]
            int vd = o - 80;
            float inv = vg[vd] * rsqrtf(vv[vd] + EPS);
            float add = vb[vd] - vm[vd] * inv;
#pragma unroll
            for (int i = 0; i < 4; i++)
                v_out[(b * M_ + mbase + i) * DV + vd] = acc[i][j] * inv + add;
        }
    }
}

// ---------------- Kernel 2: softmax over M per (b,k) row, in place ---------
__global__ __launch_bounds__(256) void k_softmax(float* __restrict__ kl)
{
    float* p = kl + (size_t)blockIdx.x * M_;
    const int tid = threadIdx.x;
    float v[4];
    float mx = -1e30f;
#pragma unroll
    for (int i = 0; i < 4; i++) { v[i] = p[tid + 256 * i]; mx = fmaxf(mx, v[i]); }
#pragma unroll
    for (int off = 32; off >= 1; off >>= 1) mx = fmaxf(mx, __shfl_xor(mx, off));
    __shared__ float red[8];
    if ((tid & 63) == 0) red[tid >> 6] = mx;
    __syncthreads();
    mx = fmaxf(fmaxf(red[0], red[1]), fmaxf(red[2], red[3]));
    float s = 0.f;
#pragma unroll
    for (int i = 0; i < 4; i++) { v[i] = __expf(v[i] - mx); s += v[i]; }
#pragma unroll
    for (int off = 32; off >= 1; off >>= 1) s += __shfl_xor(s, off);
    if ((tid & 63) == 0) red[4 + (tid >> 6)] = s;
    __syncthreads();
    s = red[4] + red[5] + red[6] + red[7];
    float inv = 1.f / s;
#pragma unroll
    for (int i = 0; i < 4; i++) p[tid + 256 * i] = v[i] * inv;
}

// ---------------- Kernel 3: content_lam[b,k,vd] = sum_m ksm * v ------------
__global__ __launch_bounds__(256) void k_clam(
    const float* __restrict__ ksm, const float* __restrict__ vbn,
    float* __restrict__ clam)
{
    const int b   = blockIdx.x >> 3;
    const int m0  = (blockIdx.x & 7) * 128;
    const int tid = threadIdx.x;
    const int vd  = tid & 63;
    const int kq  = tid >> 6;
    float acc[4] = {0.f, 0.f, 0.f, 0.f};
    for (int mi = 0; mi < 128; mi++) {
        const int m = m0 + mi;
        const float vvv = vbn[(b * M_ + m) * DV + vd];
#pragma unroll
        for (int j = 0; j < 4; j++)
            acc[j] = fmaf(ksm[(b * DK + kq + 4 * j) * M_ + m], vvv, acc[j]);
    }
#pragma unroll
    for (int j = 0; j < 4; j++)
        atomicAdd(&clam[(b * DK + kq + 4 * j) * DV + vd], acc[j]);
}

// ---------------- Kernel 4: fused 7x7 conv (pos_lam) + final matmul --------
// Round-5 design at the PROVEN register config: plain __launch_bounds__(512),
// NO second arg (rounds 4/5/7 all spilled at VGPR=64; round 3's 512-plain
// compiled to VGPR=128, zero spill).
// grid 32 b * 16 row-pairs.  512 thr: vd=tid&63, pg=tid>>6 (4 px).
// v read DIRECT from global (LLC-resident; 256B-coalesced per column) into
// vr[10] regs.  LDS: ostage[64][132]+lw+cl ~41 KB -> 3 blocks/CU = 6 w/SIMD.
__global__ __launch_bounds__(512) void k_fuse(
    const float* __restrict__ vbn, const float* __restrict__ qbn,
    const float* __restrict__ clam,
    const float* __restrict__ lw, const float* __restrict__ lb,
    float* __restrict__ out)
{
    __shared__ float ostage[64][132];      // 33.8 KB; stride%4==0 -> b128 ok
    __shared__ float lw_s[16 * 49];
    __shared__ float cl_s[16 * 64];
    __shared__ float lb_s[16];

    const int b   = blockIdx.x >> 4;
    const int rt  = blockIdx.x & 15;
    const int h0  = rt * 2;
    const int tid = threadIdx.x;

    for (int i = tid; i < 784; i += 512) lw_s[i] = lw[i];
    if (tid < 256)
        *reinterpret_cast<float4*>(&cl_s[tid * 4]) =
            *reinterpret_cast<const float4*>(&clam[b * DK * DV + tid * 4]);
    if (tid < 16) lb_s[tid] = lb[tid];
    __syncthreads();

    const int vd  = tid & 63;
    const int pg  = tid >> 6;       // 0..7: pixel column group
    const int px0 = pg * 4;
    const float* vb_b = vbn + (size_t)b * M_ * DV + vd;

    for (int grp = 0; grp < 2; grp++) {     // output row h0+grp
        float plam[4][16];
#pragma unroll
        for (int ip = 0; ip < 4; ip++)
#pragma unroll
            for (int k = 0; k < 16; k++) plam[ip][k] = 0.f;

#pragma unroll
        for (int dy = 0; dy < 7; dy++) {
            const int gr = h0 + grp - 3 + dy;      // global row (block-uniform)
            float vr[10];                          // cols px0-3 .. px0+6
            if (gr >= 0 && gr < H_) {
#pragma unroll
                for (int j = 0; j < 10; j++) {
                    const int col = px0 - 3 + j;   // wave-uniform validity
                    vr[j] = (col >= 0 && col < W_)
                          ? vb_b[(gr * W_ + col) * DV] : 0.f;
                }
            } else {
#pragma unroll
                for (int j = 0; j < 10; j++) vr[j] = 0.f;
            }
#pragma unroll
            for (int dx = 0; dx < 7; dx++) {
                float lwv[16];
#pragma unroll
                for (int k = 0; k < 16; k++) lwv[k] = lw_s[k * 49 + dy * 7 + dx];
#pragma unroll
                for (int ip = 0; ip < 4; ip++) {
                    const float vv = vr[ip + dx];
#pragma unroll
                    for (int k = 0; k < 16; k++)
                        plam[ip][k] = fmaf(vv, lwv[k], plam[ip][k]);
                }
            }
        }
        // epilogue: 4 pixels -> ostage[vd][p*4..p*4+3]
        const int mrow = (h0 + grp) * W_;
#pragma unroll
        for (int ip = 0; ip < 4; ip++) {
            const int p = px0 + ip;                // 0..31 within row
            const int m = mrow + p;
            float lamv[16];
#pragma unroll
            for (int k = 0; k < 16; k++)
                lamv[k] = plam[ip][k] + cl_s[k * DV + vd] + lb_s[k];
            const float* qp = qbn + (size_t)(b * M_ + m) * NH * DK;
            float4 ov;
            float* ovp = reinterpret_cast<float*>(&ov);
#pragma unroll
            for (int n = 0; n < 4; n++) {
                const float4* q4 = reinterpret_cast<const float4*>(qp + n * DK);
                float4 qa = q4[0], qb4 = q4[1], qc = q4[2], qd = q4[3];
                ovp[n] = qa.x * lamv[0] + qa.y * lamv[1] + qa.z * lamv[2] + qa.w * lamv[3]
                       + qb4.x * lamv[4] + qb4.y * lamv[5] + qb4.z * lamv[6] + qb4.w * lamv[7]
                       + qc.x * lamv[8] + qc.y * lamv[9] + qc.z * lamv[10] + qc.w * lamv[11]
                       + qd.x * lamv[12] + qd.y * lamv[13] + qd.z * lamv[14] + qd.w * lamv[15];
            }
            *reinterpret_cast<float4*>(&ostage[vd][p * 4]) = ov;
        }
        __syncthreads();
        // flush this row: 2048 float4, lanes consecutive -> coalesced
        {
            const int mrow4 = mrow * 4;
            for (int i4 = tid; i4 < 2048; i4 += 512) {
                const int vdw  = i4 >> 5;          // 32 float4 per vd
                const int off4 = (i4 & 31) * 4;
                float4 val = *reinterpret_cast<const float4*>(&ostage[vdw][off4]);
                *reinterpret_cast<float4*>(
                    out + (size_t)b * (C_ * M_) + (size_t)vdw * 4096 + mrow4 + off4) = val;
            }
        }
        __syncthreads();
    }
}

extern "C" void kernel_launch(void* const* d_in, const int* in_sizes, int n_in,
                              void* d_out, int out_size, void* d_ws, size_t ws_size,
                              hipStream_t stream)
{
    (void)in_sizes; (void)n_in; (void)out_size; (void)ws_size;
    const float* x   = (const float*)d_in[0];
    const float* w   = (const float*)d_in[1];
    const float* qg  = (const float*)d_in[2];
    const float* qb  = (const float*)d_in[3];
    const float* qm  = (const float*)d_in[4];
    const float* qvr = (const float*)d_in[5];
    const float* vg  = (const float*)d_in[6];
    const float* vb  = (const float*)d_in[7];
    const float* vm  = (const float*)d_in[8];
    const float* vvr = (const float*)d_in[9];
    const float* lw  = (const float*)d_in[10];
    const float* lb  = (const float*)d_in[11];
    float* out = (float*)d_out;

    float* ws   = (float*)d_ws;
    float* q_bn = ws;                  // [b][m][n][k]  2,097,152 f
    float* v_bn = ws + 2097152;        // [b][m][vd]    2,097,152 f
    float* k_bf = ws + 4194304;        // [b][k][m]       524,288 f (in-place sm)
    float* clam = ws + 4718592;        // [b][k][vd]       32,768 f

    hipMemsetAsync(clam, 0, 32768 * sizeof(float), stream);
    hipLaunchKernelGGL(k_qkv, dim3(512), dim3(256), 0, stream,
                       x, w, qg, qb, qm, qvr, vg, vb, vm, vvr, q_bn, k_bf, v_bn);
    hipLaunchKernelGGL(k_softmax, dim3(512), dim3(256), 0, stream, k_bf);
    hipLaunchKernelGGL(k_clam, dim3(256), dim3(256), 0, stream, k_bf, v_bn, clam);
    hipLaunchKernelGGL(k_fuse, dim3(512), dim3(512), 0, stream,
                       v_bn, q_bn, clam, lw, lb, out);
}

// Round 9
// 125.773 us; speedup vs baseline: 7.4336x; 5.4806x over previous
//
#include <hip/hip_runtime.h>

constexpr int B_ = 32, C_ = 256, H_ = 32, W_ = 32, M_ = 1024;
constexpr int NH = 4, DK = 16, DV = 64;
constexpr float EPS = 1e-5f;

// ---------------- Kernel 1: qkv = W(144x256) @ x(256xM) per batch, + BN ----
__global__ __launch_bounds__(256) void k_qkv(
    const float* __restrict__ x, const float* __restrict__ w,
    const float* __restrict__ qg, const float* __restrict__ qb,
    const float* __restrict__ qm, const float* __restrict__ qv,
    const float* __restrict__ vg, const float* __restrict__ vb,
    const float* __restrict__ vm, const float* __restrict__ vv,
    float* __restrict__ q_out, float* __restrict__ k_out,
    float* __restrict__ v_out)
{
    __shared__ float xs[64][64];    // 16 KB
    __shared__ float wsh[144][64];  // 36.9 KB
    const int b   = blockIdx.x >> 4;
    const int m0  = (blockIdx.x & 15) * 64;
    const int tid = threadIdx.x;
    const int ml  = tid & 15;
    const int og  = tid >> 4;

    float acc[4][9];
#pragma unroll
    for (int i = 0; i < 4; i++)
#pragma unroll
        for (int j = 0; j < 9; j++) acc[i][j] = 0.f;

    for (int c0 = 0; c0 < C_; c0 += 64) {
        __syncthreads();
#pragma unroll
        for (int i = 0; i < 4; i++) {            // 4096 x = 1024 float4
            int f4 = tid + 256 * i;
            int ci = f4 >> 4, mf = (f4 & 15) * 4;
            *reinterpret_cast<float4*>(&xs[ci][mf]) =
                *reinterpret_cast<const float4*>(&x[(b * C_ + c0 + ci) * M_ + m0 + mf]);
        }
#pragma unroll
        for (int i = 0; i < 9; i++) {            // 9216 w = 2304 float4
            int f4 = tid + 256 * i;
            int o = f4 >> 4, cf = (f4 & 15) * 4;
            *reinterpret_cast<float4*>(&wsh[o][cf]) =
                *reinterpret_cast<const float4*>(&w[o * C_ + c0 + cf]);
        }
        __syncthreads();
#pragma unroll 2
        for (int ci = 0; ci < 64; ci++) {
            float4 xv = *reinterpret_cast<const float4*>(&xs[ci][ml * 4]);
#pragma unroll
            for (int j = 0; j < 9; j++) {
                float wv = wsh[og + 16 * j][ci];
                acc[0][j] = fmaf(wv, xv.x, acc[0][j]);
                acc[1][j] = fmaf(wv, xv.y, acc[1][j]);
                acc[2][j] = fmaf(wv, xv.z, acc[2][j]);
                acc[3][j] = fmaf(wv, xv.w, acc[3][j]);
            }
        }
    }

    const int mbase = m0 + ml * 4;
#pragma unroll
    for (int j = 0; j < 9; j++) {
        const int o = og + 16 * j;
        if (o < 64) {                         // q channel: BN then [b][m][n][k]
            float inv = qg[o] * rsqrtf(qv[o] + EPS);
            float add = qb[o] - qm[o] * inv;
            int n = o >> 4, k = o & 15;
#pragma unroll
            for (int i = 0; i < 4; i++)
                q_out[((b * M_ + mbase + i) * NH + n) * DK + k] =
                    acc[i][j] * inv + add;
        } else if (o < 80) {                  // k logits: [b][k][m]
            int kk = o - 64;
#pragma unroll
            for (int i = 0; i < 4; i++)
                k_out[(b * DK + kk) * M_ + mbase + i] = acc[i][j];
        } else {                              // v channel: BN then [b][m][vd]
            int vd = o - 80;
            float inv = vg[vd] * rsqrtf(vv[vd] + EPS);
            float add = vb[vd] - vm[vd] * inv;
#pragma unroll
            for (int i = 0; i < 4; i++)
                v_out[(b * M_ + mbase + i) * DV + vd] = acc[i][j] * inv + add;
        }
    }
}

// ---------------- Kernel 2: softmax over M per (b,k) row, in place ---------
__global__ __launch_bounds__(256) void k_softmax(float* __restrict__ kl)
{
    float* p = kl + (size_t)blockIdx.x * M_;
    const int tid = threadIdx.x;
    float v[4];
    float mx = -1e30f;
#pragma unroll
    for (int i = 0; i < 4; i++) { v[i] = p[tid + 256 * i]; mx = fmaxf(mx, v[i]); }
#pragma unroll
    for (int off = 32; off >= 1; off >>= 1) mx = fmaxf(mx, __shfl_xor(mx, off));
    __shared__ float red[8];
    if ((tid & 63) == 0) red[tid >> 6] = mx;
    __syncthreads();
    mx = fmaxf(fmaxf(red[0], red[1]), fmaxf(red[2], red[3]));
    float s = 0.f;
#pragma unroll
    for (int i = 0; i < 4; i++) { v[i] = __expf(v[i] - mx); s += v[i]; }
#pragma unroll
    for (int off = 32; off >= 1; off >>= 1) s += __shfl_xor(s, off);
    if ((tid & 63) == 0) red[4 + (tid >> 6)] = s;
    __syncthreads();
    s = red[4] + red[5] + red[6] + red[7];
    float inv = 1.f / s;
#pragma unroll
    for (int i = 0; i < 4; i++) p[tid + 256 * i] = v[i] * inv;
}

// ---------------- Kernel 3: content_lam[b,k,vd] = sum_m ksm * v ------------
__global__ __launch_bounds__(256) void k_clam(
    const float* __restrict__ ksm, const float* __restrict__ vbn,
    float* __restrict__ clam)
{
    const int b   = blockIdx.x >> 3;
    const int m0  = (blockIdx.x & 7) * 128;
    const int tid = threadIdx.x;
    const int vd  = tid & 63;
    const int kq  = tid >> 6;
    float acc[4] = {0.f, 0.f, 0.f, 0.f};
    for (int mi = 0; mi < 128; mi++) {
        const int m = m0 + mi;
        const float vvv = vbn[(b * M_ + m) * DV + vd];
#pragma unroll
        for (int j = 0; j < 4; j++)
            acc[j] = fmaf(ksm[(b * DK + kq + 4 * j) * M_ + m], vvv, acc[j]);
    }
#pragma unroll
    for (int j = 0; j < 4; j++)
        atomicAdd(&clam[(b * DK + kq + 4 * j) * DV + vd], acc[j]);
}

// ---------------- Kernel 4: fused 7x7 conv (pos_lam) + final matmul --------
// ROUND-3 STRUCTURE (proven: VGPR 128 no-spill, FETCH 16MB, WRITE 36MB) with
// two LDS-issue-diet changes:
//   (a) lam_w transposed in LDS -> lw_t[tap][16k]: 4x ds_read_b128 per tap
//       (was 16x b32) -> weight reads 784->196 per grp.
//   (b) vr[10] per-dy register window from v_s (LDS, short-latency) ->
//       v reads 196->70 per grp.  dy loop NOT unrolled (unroll 1) so load
//       live-ranges never merge across iterations (round-8 spill lesson).
// grid 32 b * 8 tiles of 4 rows.  512 thr: vd=tid&63, pg=tid>>6.
__global__ __launch_bounds__(512) void k_fuse(
    const float* __restrict__ vbn, const float* __restrict__ qbn,
    const float* __restrict__ clam,
    const float* __restrict__ lw, const float* __restrict__ lb,
    float* __restrict__ out)
{
    __shared__ float v_s[10 * 32 * 64];    // 80 KB: global rows h0-3 .. h0+6
    __shared__ float ostage[64][260];      // 66.6 KB; stride%4==0 -> b128 ok
    __shared__ float lw_t[49 * 16];        // 3.1 KB, [tap][k] (transposed)
    __shared__ float cl_s[16 * 64];        // 4 KB
    __shared__ float lb_s[16];

    const int b   = blockIdx.x >> 3;
    const int rt  = blockIdx.x & 7;
    const int h0  = rt * 4;
    const int tid = threadIdx.x;

    for (int i4 = tid; i4 < 5120; i4 += 512) {   // 20480 floats as float4
        int r   = i4 >> 9;                 // staged row 0..9 = global h0-3+r
        int rem = (i4 & 511) * 4;
        int gr  = h0 - 3 + r;
        float4 val = make_float4(0.f, 0.f, 0.f, 0.f);
        if (gr >= 0 && gr < H_)
            val = *reinterpret_cast<const float4*>(&vbn[(b * M_ + gr * W_) * DV + rem]);
        *reinterpret_cast<float4*>(&v_s[r * 2048 + rem]) = val;
    }
    for (int i = tid; i < 784; i += 512) {       // transpose: [k][tap]->[tap][k]
        int tap = i >> 4, k = i & 15;
        lw_t[i] = lw[k * 49 + tap];
    }
    if (tid < 256)
        *reinterpret_cast<float4*>(&cl_s[tid * 4]) =
            *reinterpret_cast<const float4*>(&clam[b * DK * DV + tid * 4]);
    if (tid < 16) lb_s[tid] = lb[tid];
    __syncthreads();

    const int vd  = tid & 63;
    const int pg  = tid >> 6;       // wave index: pixel column group
    const int px0 = pg * 4;

    for (int grp = 0; grp < 4; grp++) {     // grp = pixel row within tile
        float plam[4][16];
#pragma unroll
        for (int ip = 0; ip < 4; ip++)
#pragma unroll
            for (int k = 0; k < 16; k++) plam[ip][k] = 0.f;

#pragma unroll 1
        for (int dy = 0; dy < 7; dy++) {
            const int rbase = (grp + dy) * W_;   // staged row index * 32
            float vr[10];                        // cols px0-3 .. px0+6
#pragma unroll
            for (int j = 0; j < 10; j++) {
                const int col = px0 - 3 + j;     // wave-uniform validity
                vr[j] = (col >= 0 && col < W_) ? v_s[(rbase + col) * DV + vd] : 0.f;
            }
#pragma unroll
            for (int dx = 0; dx < 7; dx++) {
                const float* lwp = &lw_t[(dy * 7 + dx) * 16];
                float4 l0 = *reinterpret_cast<const float4*>(lwp);
                float4 l1 = *reinterpret_cast<const float4*>(lwp + 4);
                float4 l2 = *reinterpret_cast<const float4*>(lwp + 8);
                float4 l3 = *reinterpret_cast<const float4*>(lwp + 12);
                const float lwv[16] = {l0.x, l0.y, l0.z, l0.w, l1.x, l1.y, l1.z, l1.w,
                                       l2.x, l2.y, l2.z, l2.w, l3.x, l3.y, l3.z, l3.w};
#pragma unroll
                for (int ip = 0; ip < 4; ip++) {
                    const float vvv = vr[ip + dx];
#pragma unroll
                    for (int k = 0; k < 16; k++)
                        plam[ip][k] = fmaf(vvv, lwv[k], plam[ip][k]);
                }
            }
        }
        // epilogue: 4 pixels of this group
#pragma unroll
        for (int ip = 0; ip < 4; ip++) {
            const int p = grp * 32 + px0 + ip;     // 0..127 within tile
            const int m = h0 * W_ + p;
            float lamv[16];
#pragma unroll
            for (int k = 0; k < 16; k++)
                lamv[k] = plam[ip][k] + cl_s[k * DV + vd] + lb_s[k];
            const float* qp = qbn + (size_t)(b * M_ + m) * NH * DK;
            float4 ov;
            float* ovp = reinterpret_cast<float*>(&ov);
#pragma unroll
            for (int n = 0; n < 4; n++) {
                const float4* q4 = reinterpret_cast<const float4*>(qp + n * DK);
                float4 qa = q4[0], qb4 = q4[1], qc = q4[2], qd = q4[3];
                ovp[n] = qa.x * lamv[0] + qa.y * lamv[1] + qa.z * lamv[2] + qa.w * lamv[3]
                       + qb4.x * lamv[4] + qb4.y * lamv[5] + qb4.z * lamv[6] + qb4.w * lamv[7]
                       + qc.x * lamv[8] + qc.y * lamv[9] + qc.z * lamv[10] + qc.w * lamv[11]
                       + qd.x * lamv[12] + qd.y * lamv[13] + qd.z * lamv[14] + qd.w * lamv[15];
            }
            *reinterpret_cast<float4*>(&ostage[vd][(p & 63) * 4]) = ov;
        }
        if (grp & 1) {                      // flush 64 pixels, coalesced
            __syncthreads();
            const int half = grp >> 1;
            const int mb4 = (h0 + half * 2) * W_ * 4;
            for (int i = tid; i < 4096; i += 512) {
                const int vdw  = i >> 6;
                const int off4 = (i & 63) * 4;
                float4 val = *reinterpret_cast<const float4*>(&ostage[vdw][off4]);
                *reinterpret_cast<float4*>(
                    out + (size_t)b * (C_ * M_) + (size_t)vdw * 4096 + mb4 + off4) = val;
            }
            __syncthreads();
        }
    }
}

extern "C" void kernel_launch(void* const* d_in, const int* in_sizes, int n_in,
                              void* d_out, int out_size, void* d_ws, size_t ws_size,
                              hipStream_t stream)
{
    (void)in_sizes; (void)n_in; (void)out_size; (void)ws_size;
    const float* x   = (const float*)d_in[0];
    const float* w   = (const float*)d_in[1];
    const float* qg  = (const float*)d_in[2];
    const float* qb  = (const float*)d_in[3];
    const float* qm  = (const float*)d_in[4];
    const float* qvr = (const float*)d_in[5];
    const float* vg  = (const float*)d_in[6];
    const float* vb  = (const float*)d_in[7];
    const float* vm  = (const float*)d_in[8];
    const float* vvr = (const float*)d_in[9];
    const float* lw  = (const float*)d_in[10];
    const float* lb  = (const float*)d_in[11];
    float* out = (float*)d_out;

    float* ws   = (float*)d_ws;
    float* q_bn = ws;                  // [b][m][n][k]  2,097,152 f
    float* v_bn = ws + 2097152;        // [b][m][vd]    2,097,152 f
    float* k_bf = ws + 4194304;        // [b][k][m]       524,288 f (in-place sm)
    float* clam = ws + 4718592;        // [b][k][vd]       32,768 f

    hipMemsetAsync(clam, 0, 32768 * sizeof(float), stream);
    hipLaunchKernelGGL(k_qkv, dim3(512), dim3(256), 0, stream,
                       x, w, qg, qb, qm, qvr, vg, vb, vm, vvr, q_bn, k_bf, v_bn);
    hipLaunchKernelGGL(k_softmax, dim3(512), dim3(256), 0, stream, k_bf);
    hipLaunchKernelGGL(k_clam, dim3(256), dim3(256), 0, stream, k_bf, v_bn, clam);
    hipLaunchKernelGGL(k_fuse, dim3(256), dim3(512), 0, stream,
                       v_bn, q_bn, clam, lw, lb, out);
}